// Round 1
// baseline (390.009 us; speedup 1.0000x reference)
//
#include <hip/hip_runtime.h>
#include <hip/hip_bf16.h>

// Swin-V2 window attention, fused. B=2048 windows, N=64 tokens, C=256, H=8, Dh=32.
// Plan:
//   cpb_kernel:   CPB MLP -> 16*sigmoid bias, expanded into MFMA C-frag layout; scale[h].
//   convert_kernel: qkv_weight/proj_w -> bf16; concat qkv bias (q_bias | 0 | v_bias).
//   win_attn_kernel: 1 block per window, 4 waves, wave owns heads {w, w+4}.
//     QKV via mfma(W,x^T) (q,k swapped -> packed transposed stores) / mfma(x,Wv) for v,
//     cosine-norm epilogue, QK^T + bias + softmax, PV as out^T = v^T P^T, proj GEMM.
// All matmuls: mfma_f32_16x16x32_bf16; C/D: col=lane&15, row=(lane>>4)*4+reg;
// A/B frag: M[lane&15][(lane>>4)*8 + j] (contiguous 8 bf16 = 16B ds_read_b128).

typedef __attribute__((ext_vector_type(8))) short bf16x8;
typedef __attribute__((ext_vector_type(4))) short short4v;
typedef __attribute__((ext_vector_type(4))) float f32x4;

__device__ __forceinline__ unsigned short f2bf(float f) {
  union { float f; unsigned int u; } a; a.f = f;
  return (unsigned short)((a.u + 0x7FFFu + ((a.u >> 16) & 1u)) >> 16);  // RNE
}

// ---------------- CPB MLP + scale precompute ----------------
__global__ void cpb_kernel(const float* __restrict__ w1, const float* __restrict__ b1,
                           const float* __restrict__ w2, const float* __restrict__ ls,
                           float* __restrict__ rpb, float* __restrict__ scale)
{
  __shared__ float bt[127 * 8];
  const int tid = threadIdx.x;
  if (tid < 127) {
    float xr = ((float)tid - 63.0f) * (8.0f / 63.0f);
    float sgn = (xr > 0.0f) ? 1.0f : ((xr < 0.0f) ? -1.0f : 0.0f);
    float val = sgn * log2f(fabsf(xr) + 1.0f) * (1.0f / 3.0f);  // /log2(8)
    float acc[8];
    #pragma unroll
    for (int hh = 0; hh < 8; ++hh) acc[hh] = 0.0f;
    for (int j = 0; j < 512; ++j) {
      float hv = fmaxf(val * w1[j] + b1[j], 0.0f);
      #pragma unroll
      for (int hh = 0; hh < 8; ++hh) acc[hh] += hv * w2[hh * 512 + j];
    }
    #pragma unroll
    for (int hh = 0; hh < 8; ++hh) bt[tid * 8 + hh] = acc[hh];
  }
  if (tid < 8) scale[tid] = __expf(fminf(ls[tid], 4.605170185988091f));  // ln(100)
  __syncthreads();
  // expand to rpb[h][mt][nt][lane][r] = 16*sigmoid(bt[row-col+63][h])
  for (int i = tid; i < 32768; i += 256) {
    int r = i & 3, lane = (i >> 2) & 63, nt = (i >> 8) & 3, mt = (i >> 10) & 3, hh = i >> 12;
    int row = mt * 16 + (lane >> 4) * 4 + r;
    int col = nt * 16 + (lane & 15);
    float b = bt[(row - col + 63) * 8 + hh];
    rpb[i] = 16.0f / (1.0f + __expf(-b));
  }
}

// ---------------- weight conversion ----------------
__global__ void convert_kernel(const float* __restrict__ qw, const float* __restrict__ pw,
                               const float* __restrict__ qb, const float* __restrict__ vb,
                               short* __restrict__ wqkv, short* __restrict__ wproj,
                               float* __restrict__ qkvb)
{
  const int idx = blockIdx.x * 256 + threadIdx.x;
  if (idx < 196608) wqkv[idx] = (short)f2bf(qw[idx]);
  else if (idx - 196608 < 65536) wproj[idx - 196608] = (short)f2bf(pw[idx - 196608]);
  if (idx < 768) qkvb[idx] = (idx < 256) ? qb[idx] : ((idx < 512) ? 0.0f : vb[idx - 512]);
}

// ---------------- fused window attention ----------------
__global__ __launch_bounds__(256, 1) void win_attn_kernel(
    const float* __restrict__ x,
    const short* __restrict__ wqkv,
    const short* __restrict__ wproj,
    const float* __restrict__ qkvb,
    const float* __restrict__ scale,
    const float* __restrict__ rpb,
    const float* __restrict__ projb,
    float* __restrict__ out)
{
  __shared__ short xb[64 * 264];        // x tile bf16, row stride 264 (pad)
  __shared__ short wbuf[4][7424];       // per wave: q[0:2560) k[2560:5120) vt[5120:7424); P overlays [0:4608)
  __shared__ short ob[64 * 264];        // attention output tile bf16

  const int tid = threadIdx.x;
  const int wid = tid >> 6;
  const int lane = tid & 63;
  const int lq = lane & 15;
  const int lg = lane >> 4;
  const int blk = blockIdx.x;

  // ---- stage x tile (64x256 f32 -> bf16 LDS) ----
  {
    const int r = tid >> 2;
    const int c0 = (tid & 3) * 64;
    const float4* xg = (const float4*)(x + ((size_t)blk * 64 + r) * 256 + c0);
    short* dst = &xb[r * 264 + c0];
    #pragma unroll
    for (int i = 0; i < 16; i += 2) {
      float4 a = xg[i];
      float4 b = xg[i + 1];
      bf16x8 v;
      v[0] = (short)f2bf(a.x); v[1] = (short)f2bf(a.y);
      v[2] = (short)f2bf(a.z); v[3] = (short)f2bf(a.w);
      v[4] = (short)f2bf(b.x); v[5] = (short)f2bf(b.y);
      v[6] = (short)f2bf(b.z); v[7] = (short)f2bf(b.w);
      *(bf16x8*)(dst + i * 4) = v;
    }
  }
  __syncthreads();

  short* qb  = wbuf[wid];         // qn, [token][d] stride 40
  short* kb  = qb + 2560;         // kn, [token][d] stride 40
  short* vtb = qb + 5120;         // v^T, [d][token] stride 72
  short* pb  = qb;                // P,  [row][col] stride 72 (overlays q+k)

  const f32x4 fz = {0.0f, 0.0f, 0.0f, 0.0f};

  for (int hi = 0; hi < 2; ++hi) {
    const int h = wid + hi * 4;

    // ---- QKV: sq/sk = W · x^T (q^T,k^T layout), sv = x · Wv^T (v layout) ----
    f32x4 sq[2][4], sk[2][4], sv[4][2];
    #pragma unroll
    for (int i = 0; i < 2; ++i)
      #pragma unroll
      for (int j = 0; j < 4; ++j) { sq[i][j] = fz; sk[i][j] = fz; sv[j][i] = fz; }

    for (int ks = 0; ks < 8; ++ks) {
      const int k0 = ks * 32;
      bf16x8 xf[4];
      #pragma unroll
      for (int mt = 0; mt < 4; ++mt)
        xf[mt] = *(const bf16x8*)&xb[(mt * 16 + lq) * 264 + k0 + lg * 8];
      bf16x8 wq[2], wk[2], wv[2];
      #pragma unroll
      for (int dt = 0; dt < 2; ++dt) {
        const int rw = (h * 32 + dt * 16 + lq) * 256 + k0 + lg * 8;
        wq[dt] = *(const bf16x8*)&wqkv[rw];
        wk[dt] = *(const bf16x8*)&wqkv[rw + 65536];    // +256 rows
        wv[dt] = *(const bf16x8*)&wqkv[rw + 131072];   // +512 rows
      }
      #pragma unroll
      for (int dt = 0; dt < 2; ++dt)
        #pragma unroll
        for (int mt = 0; mt < 4; ++mt) {
          sq[dt][mt] = __builtin_amdgcn_mfma_f32_16x16x32_bf16(wq[dt], xf[mt], sq[dt][mt], 0, 0, 0);
          sk[dt][mt] = __builtin_amdgcn_mfma_f32_16x16x32_bf16(wk[dt], xf[mt], sk[dt][mt], 0, 0, 0);
          sv[mt][dt] = __builtin_amdgcn_mfma_f32_16x16x32_bf16(xf[mt], wv[dt], sv[mt][dt], 0, 0, 0);
        }
    }

    // ---- q epilogue: +bias, L2-normalize rows, packed store [token][d] ----
    {
      float qbias[2][4];
      #pragma unroll
      for (int dt = 0; dt < 2; ++dt)
        #pragma unroll
        for (int r = 0; r < 4; ++r)
          qbias[dt][r] = qkvb[h * 32 + dt * 16 + lg * 4 + r];
      #pragma unroll
      for (int mt = 0; mt < 4; ++mt) {
        float vv[2][4];
        float ss = 0.0f;
        #pragma unroll
        for (int dt = 0; dt < 2; ++dt)
          #pragma unroll
          for (int r = 0; r < 4; ++r) {
            vv[dt][r] = sq[dt][mt][r] + qbias[dt][r];
            ss += vv[dt][r] * vv[dt][r];
          }
        ss += __shfl_xor(ss, 16);
        ss += __shfl_xor(ss, 32);
        float rn = 1.0f / fmaxf(sqrtf(ss), 1e-12f);
        #pragma unroll
        for (int dt = 0; dt < 2; ++dt) {
          short4v pk;
          #pragma unroll
          for (int r = 0; r < 4; ++r) pk[r] = (short)f2bf(vv[dt][r] * rn);
          *(short4v*)&qb[(mt * 16 + lq) * 40 + dt * 16 + lg * 4] = pk;
        }
      }
    }
    // ---- k epilogue (bias = 0) ----
    {
      #pragma unroll
      for (int mt = 0; mt < 4; ++mt) {
        float ss = 0.0f;
        #pragma unroll
        for (int dt = 0; dt < 2; ++dt)
          #pragma unroll
          for (int r = 0; r < 4; ++r) ss += sk[dt][mt][r] * sk[dt][mt][r];
        ss += __shfl_xor(ss, 16);
        ss += __shfl_xor(ss, 32);
        float rn = 1.0f / fmaxf(sqrtf(ss), 1e-12f);
        #pragma unroll
        for (int dt = 0; dt < 2; ++dt) {
          short4v pk;
          #pragma unroll
          for (int r = 0; r < 4; ++r) pk[r] = (short)f2bf(sk[dt][mt][r] * rn);
          *(short4v*)&kb[(mt * 16 + lq) * 40 + dt * 16 + lg * 4] = pk;
        }
      }
    }
    // ---- v epilogue: +bias, packed transposed store v^T[d][token] ----
    {
      float vb0 = qkvb[512 + h * 32 + lq];
      float vb1 = qkvb[512 + h * 32 + 16 + lq];
      #pragma unroll
      for (int mt = 0; mt < 4; ++mt) {
        short4v p0, p1;
        #pragma unroll
        for (int r = 0; r < 4; ++r) {
          p0[r] = (short)f2bf(sv[mt][0][r] + vb0);
          p1[r] = (short)f2bf(sv[mt][1][r] + vb1);
        }
        *(short4v*)&vtb[lq * 72 + mt * 16 + lg * 4] = p0;
        *(short4v*)&vtb[(16 + lq) * 72 + mt * 16 + lg * 4] = p1;
      }
    }

    // ---- QK^T (K=32, single k-step) ----
    f32x4 s[4][4];
    {
      bf16x8 a2[4], b2[4];
      #pragma unroll
      for (int mt = 0; mt < 4; ++mt)
        a2[mt] = *(const bf16x8*)&qb[(mt * 16 + lq) * 40 + lg * 8];
      #pragma unroll
      for (int nt = 0; nt < 4; ++nt)
        b2[nt] = *(const bf16x8*)&kb[(nt * 16 + lq) * 40 + lg * 8];
      #pragma unroll
      for (int mt = 0; mt < 4; ++mt)
        #pragma unroll
        for (int nt = 0; nt < 4; ++nt)
          s[mt][nt] = __builtin_amdgcn_mfma_f32_16x16x32_bf16(a2[mt], b2[nt], fz, 0, 0, 0);
    }

    // ---- softmax (scale, +rpb, rowwise over 64 cols) -> P bf16 in LDS ----
    const float sch = scale[h];
    #pragma unroll
    for (int mt = 0; mt < 4; ++mt) {
      f32x4 rp[4];
      #pragma unroll
      for (int nt = 0; nt < 4; ++nt)
        rp[nt] = ((const f32x4*)rpb)[((h * 4 + mt) * 4 + nt) * 64 + lane];
      #pragma unroll
      for (int r = 0; r < 4; ++r) {
        float v0 = s[mt][0][r] * sch + rp[0][r];
        float v1 = s[mt][1][r] * sch + rp[1][r];
        float v2 = s[mt][2][r] * sch + rp[2][r];
        float v3 = s[mt][3][r] * sch + rp[3][r];
        float mx = fmaxf(fmaxf(v0, v1), fmaxf(v2, v3));
        mx = fmaxf(mx, __shfl_xor(mx, 1));
        mx = fmaxf(mx, __shfl_xor(mx, 2));
        mx = fmaxf(mx, __shfl_xor(mx, 4));
        mx = fmaxf(mx, __shfl_xor(mx, 8));
        float e0 = __expf(v0 - mx);
        float e1 = __expf(v1 - mx);
        float e2 = __expf(v2 - mx);
        float e3 = __expf(v3 - mx);
        float sm = e0 + e1 + e2 + e3;
        sm += __shfl_xor(sm, 1);
        sm += __shfl_xor(sm, 2);
        sm += __shfl_xor(sm, 4);
        sm += __shfl_xor(sm, 8);
        float inv = 1.0f / sm;
        const int row = mt * 16 + lg * 4 + r;
        pb[row * 72 + lq]      = (short)f2bf(e0 * inv);
        pb[row * 72 + 16 + lq] = (short)f2bf(e1 * inv);
        pb[row * 72 + 32 + lq] = (short)f2bf(e2 * inv);
        pb[row * 72 + 48 + lq] = (short)f2bf(e3 * inv);
      }
    }

    // ---- PV: out^T = v^T · P^T (packed stores into ob) ----
    f32x4 ot[2][4];
    #pragma unroll
    for (int dt = 0; dt < 2; ++dt)
      #pragma unroll
      for (int mt = 0; mt < 4; ++mt) ot[dt][mt] = fz;
    #pragma unroll
    for (int kt = 0; kt < 2; ++kt) {
      bf16x8 av2[2], bp[4];
      #pragma unroll
      for (int dt = 0; dt < 2; ++dt)
        av2[dt] = *(const bf16x8*)&vtb[(dt * 16 + lq) * 72 + kt * 32 + lg * 8];
      #pragma unroll
      for (int mt = 0; mt < 4; ++mt)
        bp[mt] = *(const bf16x8*)&pb[(mt * 16 + lq) * 72 + kt * 32 + lg * 8];
      #pragma unroll
      for (int dt = 0; dt < 2; ++dt)
        #pragma unroll
        for (int mt = 0; mt < 4; ++mt)
          ot[dt][mt] = __builtin_amdgcn_mfma_f32_16x16x32_bf16(av2[dt], bp[mt], ot[dt][mt], 0, 0, 0);
    }
    #pragma unroll
    for (int dt = 0; dt < 2; ++dt)
      #pragma unroll
      for (int mt = 0; mt < 4; ++mt) {
        short4v pk;
        #pragma unroll
        for (int r = 0; r < 4; ++r) pk[r] = (short)f2bf(ot[dt][mt][r]);
        *(short4v*)&ob[(mt * 16 + lq) * 264 + h * 32 + dt * 16 + lg * 4] = pk;
      }
  }  // hi

  __syncthreads();

  // ---- proj: out = ob · Wp^T + b (wave w -> cols [w*64, w*64+64)) ----
  {
    f32x4 acc[4][4];
    #pragma unroll
    for (int mt = 0; mt < 4; ++mt)
      #pragma unroll
      for (int nt = 0; nt < 4; ++nt) acc[mt][nt] = fz;
    const int c0 = wid * 64;
    for (int ks = 0; ks < 8; ++ks) {
      const int k0 = ks * 32;
      bf16x8 a[4], b[4];
      #pragma unroll
      for (int mt = 0; mt < 4; ++mt)
        a[mt] = *(const bf16x8*)&ob[(mt * 16 + lq) * 264 + k0 + lg * 8];
      #pragma unroll
      for (int nt = 0; nt < 4; ++nt)
        b[nt] = *(const bf16x8*)&wproj[(c0 + nt * 16 + lq) * 256 + k0 + lg * 8];
      #pragma unroll
      for (int mt = 0; mt < 4; ++mt)
        #pragma unroll
        for (int nt = 0; nt < 4; ++nt)
          acc[mt][nt] = __builtin_amdgcn_mfma_f32_16x16x32_bf16(a[mt], b[nt], acc[mt][nt], 0, 0, 0);
    }
    #pragma unroll
    for (int nt = 0; nt < 4; ++nt) {
      const float pbv = projb[c0 + nt * 16 + lq];
      #pragma unroll
      for (int mt = 0; mt < 4; ++mt)
        #pragma unroll
        for (int r = 0; r < 4; ++r) {
          const int row = mt * 16 + lg * 4 + r;
          out[((size_t)blk * 64 + row) * 256 + c0 + nt * 16 + lq] = acc[mt][nt][r] + pbv;
        }
    }
  }
}

extern "C" void kernel_launch(void* const* d_in, const int* in_sizes, int n_in,
                              void* d_out, int out_size, void* d_ws, size_t ws_size,
                              hipStream_t stream) {
  const float* x     = (const float*)d_in[0];
  const float* qkvw  = (const float*)d_in[1];
  const float* qbias = (const float*)d_in[2];
  const float* vbias = (const float*)d_in[3];
  const float* ls    = (const float*)d_in[4];
  const float* w1    = (const float*)d_in[5];
  const float* b1    = (const float*)d_in[6];
  const float* w2    = (const float*)d_in[7];
  const float* pw    = (const float*)d_in[8];
  const float* pbias = (const float*)d_in[9];
  float* out = (float*)d_out;

  char* ws = (char*)d_ws;
  short* wqkv_bf  = (short*)(ws);                 // 393216 B
  short* wproj_bf = (short*)(ws + 393216);        // 131072 B
  float* rpb      = (float*)(ws + 524288);        // 131072 B
  float* scale    = (float*)(ws + 655360);        // 32 B
  float* qkvb     = (float*)(ws + 655392);        // 3072 B

  cpb_kernel<<<dim3(1), dim3(256), 0, stream>>>(w1, b1, w2, ls, rpb, scale);
  convert_kernel<<<dim3(1024), dim3(256), 0, stream>>>(qkvw, pw, qbias, vbias,
                                                       wqkv_bf, wproj_bf, qkvb);
  win_attn_kernel<<<dim3(2048), dim3(256), 0, stream>>>(x, wqkv_bf, wproj_bf, qkvb,
                                                        scale, rpb, pbias, out);
}

// Round 2
// 339.895 us; speedup vs baseline: 1.1474x; 1.1474x over previous
//
#include <hip/hip_runtime.h>
#include <hip/hip_bf16.h>

// Swin-V2 window attention, fused. B=2048 windows, N=64 tokens, C=256, H=8, Dh=32.
//   cpb_kernel:   CPB MLP -> 16*sigmoid bias in MFMA C-frag layout; scale[h].
//   convert_kernel: qkv_weight/proj_w -> bf16; concat qkv bias (q_bias | 0 | v_bias).
//   win_attn_kernel: 1 block/window, 4 waves, wave owns heads {w, w+4}.
//     x fragments loaded DIRECTLY from global f32 (L1/L2 reuse) + v_cvt_pk_bf16_f32,
//     q/k/v epilogues -> per-wave LDS, QK^T + bias + softmax, PV -> regs (otk),
//     barrier, otk -> ob (overlays per-wave buffers), barrier, proj GEMM.
//   LDS = 59,392 B -> 2 blocks/CU (was 126,976 -> 1 block/CU).
// All matmuls: mfma_f32_16x16x32_bf16; C/D: col=lane&15, row=(lane>>4)*4+reg;
// A/B frag: M[lane&15][(lane>>4)*8 + j] (contiguous 8 bf16 = 16B ds_read_b128).

typedef __attribute__((ext_vector_type(8))) short bf16x8;
typedef __attribute__((ext_vector_type(4))) short short4v;
typedef __attribute__((ext_vector_type(4))) float f32x4;

__device__ __forceinline__ unsigned short f2bf(float f) {
  union { float f; unsigned int u; } a; a.f = f;
  return (unsigned short)((a.u + 0x7FFFu + ((a.u >> 16) & 1u)) >> 16);  // RNE
}

// packed f32x2 -> bf16x2 (RNE), single VALU instr
__device__ __forceinline__ unsigned int cvt2(float lo, float hi) {
  unsigned int r;
  asm("v_cvt_pk_bf16_f32 %0, %1, %2" : "=v"(r) : "v"(lo), "v"(hi));
  return r;
}

// ---------------- CPB MLP + scale precompute ----------------
__global__ void cpb_kernel(const float* __restrict__ w1, const float* __restrict__ b1,
                           const float* __restrict__ w2, const float* __restrict__ ls,
                           float* __restrict__ rpb, float* __restrict__ scale)
{
  __shared__ float bt[127 * 8];
  const int tid = threadIdx.x;
  if (tid < 127) {
    float xr = ((float)tid - 63.0f) * (8.0f / 63.0f);
    float sgn = (xr > 0.0f) ? 1.0f : ((xr < 0.0f) ? -1.0f : 0.0f);
    float val = sgn * log2f(fabsf(xr) + 1.0f) * (1.0f / 3.0f);  // /log2(8)
    float acc[8];
    #pragma unroll
    for (int hh = 0; hh < 8; ++hh) acc[hh] = 0.0f;
    for (int j = 0; j < 512; ++j) {
      float hv = fmaxf(val * w1[j] + b1[j], 0.0f);
      #pragma unroll
      for (int hh = 0; hh < 8; ++hh) acc[hh] += hv * w2[hh * 512 + j];
    }
    #pragma unroll
    for (int hh = 0; hh < 8; ++hh) bt[tid * 8 + hh] = acc[hh];
  }
  if (tid < 8) scale[tid] = __expf(fminf(ls[tid], 4.605170185988091f));  // ln(100)
  __syncthreads();
  // expand to rpb[h][mt][nt][lane][r] = 16*sigmoid(bt[row-col+63][h])
  for (int i = tid; i < 32768; i += 256) {
    int r = i & 3, lane = (i >> 2) & 63, nt = (i >> 8) & 3, mt = (i >> 10) & 3, hh = i >> 12;
    int row = mt * 16 + (lane >> 4) * 4 + r;
    int col = nt * 16 + (lane & 15);
    float b = bt[(row - col + 63) * 8 + hh];
    rpb[i] = 16.0f / (1.0f + __expf(-b));
  }
}

// ---------------- weight conversion ----------------
__global__ void convert_kernel(const float* __restrict__ qw, const float* __restrict__ pw,
                               const float* __restrict__ qb, const float* __restrict__ vb,
                               short* __restrict__ wqkv, short* __restrict__ wproj,
                               float* __restrict__ qkvb)
{
  const int idx = blockIdx.x * 256 + threadIdx.x;
  if (idx < 196608) wqkv[idx] = (short)f2bf(qw[idx]);
  else if (idx - 196608 < 65536) wproj[idx - 196608] = (short)f2bf(pw[idx - 196608]);
  if (idx < 768) qkvb[idx] = (idx < 256) ? qb[idx] : ((idx < 512) ? 0.0f : vb[idx - 512]);
}

// ---------------- fused window attention ----------------
__global__ __launch_bounds__(256, 2) void win_attn_kernel(
    const float* __restrict__ x,
    const short* __restrict__ wqkv,
    const short* __restrict__ wproj,
    const float* __restrict__ qkvb,
    const float* __restrict__ scale,
    const float* __restrict__ rpb,
    const float* __restrict__ projb,
    float* __restrict__ out)
{
  __shared__ short wbuf[4][7424];   // per wave: q[0:2560) s40, k[2560:5120) s40,
                                    // vt[5120:7424) s72; P overlays [0:4608) s72.
                                    // ob (stride 264, 33,792 B) overlays wbuf after barrier.

  const int tid = threadIdx.x;
  const int wid = tid >> 6;
  const int lane = tid & 63;
  const int lq = lane & 15;
  const int lg = lane >> 4;
  const int blk = blockIdx.x;

  short* qb  = wbuf[wid];
  short* kb  = qb + 2560;
  short* vtb = qb + 5120;
  short* pb  = qb;
  short* ob  = &wbuf[0][0];

  const f32x4 fz = {0.0f, 0.0f, 0.0f, 0.0f};
  const float* xbase = x + ((size_t)blk * 64 + lq) * 256 + lg * 8;

  f32x4 otk[2][2][4];   // [hi][dt][mt], hi is compile-time (loop unrolled)

  #pragma unroll
  for (int hi = 0; hi < 2; ++hi) {
    const int h = wid + hi * 4;

    // ---- QKV: sq/sk = W · x^T (q^T,k^T layout), sv = x · Wv^T (v layout) ----
    f32x4 sq[2][4], sk[2][4], sv[4][2];
    #pragma unroll
    for (int i = 0; i < 2; ++i)
      #pragma unroll
      for (int j = 0; j < 4; ++j) { sq[i][j] = fz; sk[i][j] = fz; sv[j][i] = fz; }

    const short* wqb = wqkv + (h * 32 + lq) * 256 + lg * 8;

    #pragma unroll 2
    for (int ks = 0; ks < 8; ++ks) {
      const int k0 = ks * 32;
      bf16x8 xf[4];
      #pragma unroll
      for (int mt = 0; mt < 4; ++mt) {
        const float* xp = xbase + mt * 4096 + k0;
        float4 a = *(const float4*)xp;
        float4 b = *(const float4*)(xp + 4);
        union { unsigned int u[4]; bf16x8 v; } c;
        c.u[0] = cvt2(a.x, a.y); c.u[1] = cvt2(a.z, a.w);
        c.u[2] = cvt2(b.x, b.y); c.u[3] = cvt2(b.z, b.w);
        xf[mt] = c.v;
      }
      bf16x8 wqf[2], wkf[2], wvf[2];
      #pragma unroll
      for (int dt = 0; dt < 2; ++dt) {
        const short* wp = wqb + dt * 4096 + k0;
        wqf[dt] = *(const bf16x8*)wp;
        wkf[dt] = *(const bf16x8*)(wp + 65536);    // +256 rows
        wvf[dt] = *(const bf16x8*)(wp + 131072);   // +512 rows
      }
      #pragma unroll
      for (int dt = 0; dt < 2; ++dt)
        #pragma unroll
        for (int mt = 0; mt < 4; ++mt) {
          sq[dt][mt] = __builtin_amdgcn_mfma_f32_16x16x32_bf16(wqf[dt], xf[mt], sq[dt][mt], 0, 0, 0);
          sk[dt][mt] = __builtin_amdgcn_mfma_f32_16x16x32_bf16(wkf[dt], xf[mt], sk[dt][mt], 0, 0, 0);
          sv[mt][dt] = __builtin_amdgcn_mfma_f32_16x16x32_bf16(xf[mt], wvf[dt], sv[mt][dt], 0, 0, 0);
        }
    }

    // ---- q epilogue: +bias, L2-normalize rows, packed store [token][d] ----
    {
      float qbias[2][4];
      #pragma unroll
      for (int dt = 0; dt < 2; ++dt)
        #pragma unroll
        for (int r = 0; r < 4; ++r)
          qbias[dt][r] = qkvb[h * 32 + dt * 16 + lg * 4 + r];
      #pragma unroll
      for (int mt = 0; mt < 4; ++mt) {
        float vv[2][4];
        float ss = 0.0f;
        #pragma unroll
        for (int dt = 0; dt < 2; ++dt)
          #pragma unroll
          for (int r = 0; r < 4; ++r) {
            vv[dt][r] = sq[dt][mt][r] + qbias[dt][r];
            ss += vv[dt][r] * vv[dt][r];
          }
        ss += __shfl_xor(ss, 16);
        ss += __shfl_xor(ss, 32);
        float rn = 1.0f / fmaxf(sqrtf(ss), 1e-12f);
        #pragma unroll
        for (int dt = 0; dt < 2; ++dt) {
          short4v pk;
          #pragma unroll
          for (int r = 0; r < 4; ++r) pk[r] = (short)f2bf(vv[dt][r] * rn);
          *(short4v*)&qb[(mt * 16 + lq) * 40 + dt * 16 + lg * 4] = pk;
        }
      }
    }
    // ---- k epilogue (bias = 0) ----
    {
      #pragma unroll
      for (int mt = 0; mt < 4; ++mt) {
        float ss = 0.0f;
        #pragma unroll
        for (int dt = 0; dt < 2; ++dt)
          #pragma unroll
          for (int r = 0; r < 4; ++r) ss += sk[dt][mt][r] * sk[dt][mt][r];
        ss += __shfl_xor(ss, 16);
        ss += __shfl_xor(ss, 32);
        float rn = 1.0f / fmaxf(sqrtf(ss), 1e-12f);
        #pragma unroll
        for (int dt = 0; dt < 2; ++dt) {
          short4v pk;
          #pragma unroll
          for (int r = 0; r < 4; ++r) pk[r] = (short)f2bf(sk[dt][mt][r] * rn);
          *(short4v*)&kb[(mt * 16 + lq) * 40 + dt * 16 + lg * 4] = pk;
        }
      }
    }
    // ---- v epilogue: +bias, packed transposed store v^T[d][token] ----
    {
      float vb0 = qkvb[512 + h * 32 + lq];
      float vb1 = qkvb[512 + h * 32 + 16 + lq];
      #pragma unroll
      for (int mt = 0; mt < 4; ++mt) {
        short4v p0, p1;
        #pragma unroll
        for (int r = 0; r < 4; ++r) {
          p0[r] = (short)f2bf(sv[mt][0][r] + vb0);
          p1[r] = (short)f2bf(sv[mt][1][r] + vb1);
        }
        *(short4v*)&vtb[lq * 72 + mt * 16 + lg * 4] = p0;
        *(short4v*)&vtb[(16 + lq) * 72 + mt * 16 + lg * 4] = p1;
      }
    }

    // ---- QK^T (K=32, single k-step) ----
    f32x4 s[4][4];
    {
      bf16x8 a2[4], b2[4];
      #pragma unroll
      for (int mt = 0; mt < 4; ++mt)
        a2[mt] = *(const bf16x8*)&qb[(mt * 16 + lq) * 40 + lg * 8];
      #pragma unroll
      for (int nt = 0; nt < 4; ++nt)
        b2[nt] = *(const bf16x8*)&kb[(nt * 16 + lq) * 40 + lg * 8];
      #pragma unroll
      for (int mt = 0; mt < 4; ++mt)
        #pragma unroll
        for (int nt = 0; nt < 4; ++nt)
          s[mt][nt] = __builtin_amdgcn_mfma_f32_16x16x32_bf16(a2[mt], b2[nt], fz, 0, 0, 0);
    }

    // ---- softmax (scale, +rpb, rowwise over 64 cols) -> P bf16 in LDS ----
    const float sch = scale[h];
    #pragma unroll
    for (int mt = 0; mt < 4; ++mt) {
      f32x4 rp[4];
      #pragma unroll
      for (int nt = 0; nt < 4; ++nt)
        rp[nt] = ((const f32x4*)rpb)[((h * 4 + mt) * 4 + nt) * 64 + lane];
      #pragma unroll
      for (int r = 0; r < 4; ++r) {
        float v0 = s[mt][0][r] * sch + rp[0][r];
        float v1 = s[mt][1][r] * sch + rp[1][r];
        float v2 = s[mt][2][r] * sch + rp[2][r];
        float v3 = s[mt][3][r] * sch + rp[3][r];
        float mx = fmaxf(fmaxf(v0, v1), fmaxf(v2, v3));
        mx = fmaxf(mx, __shfl_xor(mx, 1));
        mx = fmaxf(mx, __shfl_xor(mx, 2));
        mx = fmaxf(mx, __shfl_xor(mx, 4));
        mx = fmaxf(mx, __shfl_xor(mx, 8));
        float e0 = __expf(v0 - mx);
        float e1 = __expf(v1 - mx);
        float e2 = __expf(v2 - mx);
        float e3 = __expf(v3 - mx);
        float sm = e0 + e1 + e2 + e3;
        sm += __shfl_xor(sm, 1);
        sm += __shfl_xor(sm, 2);
        sm += __shfl_xor(sm, 4);
        sm += __shfl_xor(sm, 8);
        float inv = 1.0f / sm;
        const int row = mt * 16 + lg * 4 + r;
        pb[row * 72 + lq]      = (short)f2bf(e0 * inv);
        pb[row * 72 + 16 + lq] = (short)f2bf(e1 * inv);
        pb[row * 72 + 32 + lq] = (short)f2bf(e2 * inv);
        pb[row * 72 + 48 + lq] = (short)f2bf(e3 * inv);
      }
    }

    // ---- PV: out^T = v^T · P^T -> registers (otk) ----
    #pragma unroll
    for (int dt = 0; dt < 2; ++dt)
      #pragma unroll
      for (int mt = 0; mt < 4; ++mt) otk[hi][dt][mt] = fz;
    #pragma unroll
    for (int kt = 0; kt < 2; ++kt) {
      bf16x8 av2[2], bp[4];
      #pragma unroll
      for (int dt = 0; dt < 2; ++dt)
        av2[dt] = *(const bf16x8*)&vtb[(dt * 16 + lq) * 72 + kt * 32 + lg * 8];
      #pragma unroll
      for (int mt = 0; mt < 4; ++mt)
        bp[mt] = *(const bf16x8*)&pb[(mt * 16 + lq) * 72 + kt * 32 + lg * 8];
      #pragma unroll
      for (int dt = 0; dt < 2; ++dt)
        #pragma unroll
        for (int mt = 0; mt < 4; ++mt)
          otk[hi][dt][mt] = __builtin_amdgcn_mfma_f32_16x16x32_bf16(av2[dt], bp[mt], otk[hi][dt][mt], 0, 0, 0);
    }
  }  // hi

  // ---- all waves done with private buffers: overlay ob on wbuf ----
  __syncthreads();
  #pragma unroll
  for (int hi = 0; hi < 2; ++hi) {
    const int h = wid + hi * 4;
    #pragma unroll
    for (int dt = 0; dt < 2; ++dt)
      #pragma unroll
      for (int mt = 0; mt < 4; ++mt) {
        short4v pk;
        #pragma unroll
        for (int r = 0; r < 4; ++r) pk[r] = (short)f2bf(otk[hi][dt][mt][r]);
        *(short4v*)&ob[(mt * 16 + lq) * 264 + h * 32 + dt * 16 + lg * 4] = pk;
      }
  }
  __syncthreads();

  // ---- proj: out = ob · Wp^T + b (wave w -> cols [w*64, w*64+64)) ----
  {
    f32x4 acc[4][4];
    #pragma unroll
    for (int mt = 0; mt < 4; ++mt)
      #pragma unroll
      for (int nt = 0; nt < 4; ++nt) acc[mt][nt] = fz;
    const int c0 = wid * 64;
    #pragma unroll 2
    for (int ks = 0; ks < 8; ++ks) {
      const int k0 = ks * 32;
      bf16x8 a[4], b[4];
      #pragma unroll
      for (int mt = 0; mt < 4; ++mt)
        a[mt] = *(const bf16x8*)&ob[(mt * 16 + lq) * 264 + k0 + lg * 8];
      #pragma unroll
      for (int nt = 0; nt < 4; ++nt)
        b[nt] = *(const bf16x8*)&wproj[(c0 + nt * 16 + lq) * 256 + k0 + lg * 8];
      #pragma unroll
      for (int mt = 0; mt < 4; ++mt)
        #pragma unroll
        for (int nt = 0; nt < 4; ++nt)
          acc[mt][nt] = __builtin_amdgcn_mfma_f32_16x16x32_bf16(a[mt], b[nt], acc[mt][nt], 0, 0, 0);
    }
    #pragma unroll
    for (int nt = 0; nt < 4; ++nt) {
      const float pbv = projb[c0 + nt * 16 + lq];
      #pragma unroll
      for (int mt = 0; mt < 4; ++mt)
        #pragma unroll
        for (int r = 0; r < 4; ++r) {
          const int row = mt * 16 + lg * 4 + r;
          out[((size_t)blk * 64 + row) * 256 + c0 + nt * 16 + lq] = acc[mt][nt][r] + pbv;
        }
    }
  }
}

extern "C" void kernel_launch(void* const* d_in, const int* in_sizes, int n_in,
                              void* d_out, int out_size, void* d_ws, size_t ws_size,
                              hipStream_t stream) {
  const float* x     = (const float*)d_in[0];
  const float* qkvw  = (const float*)d_in[1];
  const float* qbias = (const float*)d_in[2];
  const float* vbias = (const float*)d_in[3];
  const float* ls    = (const float*)d_in[4];
  const float* w1    = (const float*)d_in[5];
  const float* b1    = (const float*)d_in[6];
  const float* w2    = (const float*)d_in[7];
  const float* pw    = (const float*)d_in[8];
  const float* pbias = (const float*)d_in[9];
  float* out = (float*)d_out;

  char* ws = (char*)d_ws;
  short* wqkv_bf  = (short*)(ws);                 // 393216 B
  short* wproj_bf = (short*)(ws + 393216);        // 131072 B
  float* rpb      = (float*)(ws + 524288);        // 131072 B
  float* scale    = (float*)(ws + 655360);        // 32 B
  float* qkvb     = (float*)(ws + 655392);        // 3072 B

  cpb_kernel<<<dim3(1), dim3(256), 0, stream>>>(w1, b1, w2, ls, rpb, scale);
  convert_kernel<<<dim3(1024), dim3(256), 0, stream>>>(qkvw, pw, qbias, vbias,
                                                       wqkv_bf, wproj_bf, qkvb);
  win_attn_kernel<<<dim3(2048), dim3(256), 0, stream>>>(x, wqkv_bf, wproj_bf, qkvb,
                                                        scale, rpb, pbias, out);
}